// Round 1
// 472.968 us; speedup vs baseline: 1.0546x; 1.0546x over previous
//
#include <hip/hip_runtime.h>

// Problem constants: x,y are (16, 64, 256, 256) fp32.
#define NB 16
#define C  64
#define HW 65536          // 256*256
#define HW4 (HW / 4)      // float4 count per row (16384)
#define HALF4 (HW4 / 2)   // float4 count per half row (8192)

// clang extended vector => works with __builtin_nontemporal_load/store
typedef float f32x4 __attribute__((ext_vector_type(4)));

// ---------------------------------------------------------------------------
// Kernel 1: partial row sums of y.
// 2048 blocks: block = (row, half). Each block reduces a contiguous 128 KiB
// half-row with NON-TEMPORAL float4 loads (y has zero reuse; the harness's
// 1 GiB workspace poison has just filled L2+LLC with dirty/clean junk, so
// allocating our 268 MB stream in the caches only causes eviction churn).
// Partial sums land in ws[2048]; gemv combines them (cheap, exact-pow2 scale).
// ---------------------------------------------------------------------------
__global__ __launch_bounds__(256, 4) void mean_kernel(const float* __restrict__ y,
                                                      float* __restrict__ part) {
    const int blk  = blockIdx.x;          // row*2 + half, row = b*64 + c
    const int row  = blk >> 1;
    const int half = blk & 1;
    const f32x4* y4 = (const f32x4*)(y + (size_t)row * HW) + (size_t)half * HALF4;
    const int tid = threadIdx.x;

    f32x4 acc = {0.f, 0.f, 0.f, 0.f};
    #pragma unroll 8
    for (int k = tid; k < HALF4; k += 256) {          // 32 iterations/thread
        f32x4 v = __builtin_nontemporal_load(y4 + k);
        acc += v;
    }
    float s = (acc.x + acc.y) + (acc.z + acc.w);

    // wave-64 shuffle reduce
    #pragma unroll
    for (int off = 32; off > 0; off >>= 1)
        s += __shfl_down(s, off, 64);

    __shared__ float smem[4];
    const int lane = tid & 63, wv = tid >> 6;
    if (lane == 0) smem[wv] = s;
    __syncthreads();
    if (tid == 0)
        part[blk] = (smem[0] + smem[1]) + (smem[2] + smem[3]);  // raw sum
}

// ---------------------------------------------------------------------------
// Kernel 2: out[b,i] = sum_c x[b,c,i] * wm[b,c], wm = combined+scaled partials.
// One float4 of output per thread; 64 NON-TEMPORAL float4 loads down the c
// axis (x has zero reuse, caches are cold every iteration anyway).
// 1024 blocks (16 b * 64 column-chunks) x 256 threads.
// unroll 16 keeps ~16 KiB/wave in flight; launch_bounds(256,4) caps VGPR<=128
// so all 4 blocks/CU stay resident (16 waves/CU latency hiding).
// ---------------------------------------------------------------------------
__global__ __launch_bounds__(256, 4) void gemv_kernel(const float* __restrict__ x,
                                                      const float* __restrict__ part,
                                                      float* __restrict__ out) {
    const int b  = blockIdx.x >> 6;                        // 64 blocks per batch
    const int i4 = ((blockIdx.x & 63) << 8) + threadIdx.x; // float4 idx in [0,16384)

    __shared__ float ps[2 * C];
    __shared__ float ws[C];
    if (threadIdx.x < 2 * C)
        ps[threadIdx.x] = part[(b << 7) + threadIdx.x];    // b*128 + 2c + half
    __syncthreads();
    if (threadIdx.x < C) {
        // fold mean (2^-16) AND final scale (2^-22): both exact pow2 -> bit-exact
        ws[threadIdx.x] = (ps[2 * threadIdx.x] + ps[2 * threadIdx.x + 1])
                          * (1.0f / HW) * (1.0f / ((float)HW * (float)C));
    }
    __syncthreads();

    const f32x4* x4 = (const f32x4*)x + (size_t)b * (C * (size_t)HW4) + i4;

    f32x4 acc = {0.f, 0.f, 0.f, 0.f};
    #pragma unroll 16
    for (int d = 0; d < C; ++d) {
        f32x4 v = __builtin_nontemporal_load(x4 + (size_t)d * HW4);
        acc += v * ws[d];
    }

    __builtin_nontemporal_store(acc, (f32x4*)out + (size_t)b * HW4 + i4);
}

extern "C" void kernel_launch(void* const* d_in, const int* in_sizes, int n_in,
                              void* d_out, int out_size, void* d_ws, size_t ws_size,
                              hipStream_t stream) {
    const float* x = (const float*)d_in[0];
    const float* y = (const float*)d_in[1];
    float* out = (float*)d_out;
    float* part = (float*)d_ws;   // 2048 floats = 8 KiB scratch

    mean_kernel<<<dim3(NB * C * 2), dim3(256), 0, stream>>>(y, part);
    gemv_kernel<<<dim3(NB * C), dim3(256), 0, stream>>>(x, part, out);
}